// Round 1
// baseline (1636.668 us; speedup 1.0000x reference)
//
#include <hip/hip_runtime.h>

#define B_N 131072

using bfrag_t = __attribute__((ext_vector_type(8))) short;  // 8 bf16 (MFMA A/B frag)
using acc_t   = __attribute__((ext_vector_type(4))) float;  // 4 fp32 (MFMA C/D frag)
using v4f     = __attribute__((ext_vector_type(4))) float;
using i32x4_t = __attribute__((ext_vector_type(4))) int;

__device__ __forceinline__ unsigned short f2bf(float f) {
  unsigned int u = __float_as_uint(f);
  u += 0x7FFFu + ((u >> 16) & 1u);   // RNE
  return (unsigned short)(u >> 16);
}

__device__ __forceinline__ unsigned int pk2bf(float x, float y) {
  return (unsigned int)f2bf(x) | ((unsigned int)f2bf(y) << 16);
}

// async global->LDS, 16B per lane; lds base must be wave-uniform (lane-linear dest)
__device__ __forceinline__ void gload_lds16(const void* g, void* l) {
  __builtin_amdgcn_global_load_lds((const __attribute__((address_space(1))) void*)g,
                                   (__attribute__((address_space(3))) void*)l, 16, 0, 0);
}

// exact GELU: 0.5x(1+erf(x/sqrt2)); erf via Abramowitz-Stegun 7.1.26, |eps|<=1.5e-7
__device__ __forceinline__ float gelu_f(float x) {
  float ax = fabsf(x) * 0.70710678118654752f;
  float t  = __builtin_amdgcn_rcpf(fmaf(0.3275911f, ax, 1.0f));
  float p  = fmaf(1.061405429f, t, -1.453152027f);
  p = fmaf(p, t, 1.421413741f);
  p = fmaf(p, t, -0.284496736f);
  p = fmaf(p, t, 0.254829592f);
  p = p * t;
  float e  = __expf(-ax * ax);
  float er = fmaf(-p, e, 1.0f);
  er = (x < 0.0f) ? -er : er;
  return 0.5f * x * (1.0f + er);
}

// ---------------- K1: prepack (unchanged) ----------------
__global__ __launch_bounds__(256) void prepack2_k(
    const float* __restrict__ Wr1, const float* __restrict__ br1,
    const float* __restrict__ Wr2, const float* __restrict__ br2,
    const float* __restrict__ W1, const float* __restrict__ W2,
    float* __restrict__ RW, short* __restrict__ W1s, short* __restrict__ W2s) {
  int gt = blockIdx.x * 256 + threadIdx.x;   // grid 64 -> 16384 threads
  for (int idx = gt; idx < 142 * 64; idx += 16384) {
    int row = idx >> 6, j = idx & 63; float val;
    if (row < 136)      val = Wr1[row * 64 + j];
    else if (row == 136) val = br1[j];
    else if (row < 141) val = Wr2[(row - 137) * 64 + j];
    else                val = (j < 4) ? br2[j] : 0.0f;
    RW[idx] = val;
  }
  for (int ch = gt; ch < 8192; ch += 16384) {  // W1: (4,128,128) [t][k][n]
    int t = ch >> 11, r = (ch >> 4) & 127, c = ch & 15;
    const float* src = W1 + t * 16384 + r;     // stride 128 over k
    short* dst = W1s + (t * 128 + r) * 128 + ((c ^ (r & 15)) * 8);
    #pragma unroll
    for (int m = 0; m < 8; m++) dst[m] = (short)f2bf(src[(c * 8 + m) * 128]);
  }
  for (int ch = gt; ch < 4096; ch += 16384) {  // W2: (4,128,64) [t][k][d]
    int t = ch >> 10, d = (ch >> 4) & 63, c = ch & 15;
    const float* src = W2 + t * 8192 + d;      // stride 64 over k
    short* dst = W2s + (t * 64 + d) * 128 + ((c ^ (d & 15)) * 8);
    #pragma unroll
    for (int m = 0; m < 8; m++) dst[m] = (short)f2bf(src[(c * 8 + m) * 64]);
  }
}

// ---------------- K2: router v5 — quad layout, coalesced, bit-identical sequence --
// lane = (s4 = lane>>2 sample-of-16, jq = lane&3 channel quarter). Each wave: 16
// samples/pass, 2 passes. Per output channel j = jq*16+ch the fp32 fma sequence is
// IDENTICAL to the round-1/round-6 passing kernel: br1 -> a_i*W[i] (i asc) ->
// b_i*W[64+i] -> pos (acc1); b_i*W[i] -> a_i*W[64+i] -> pos (acc2); gelu; layer2
// br2 + h_j asc. x_i broadcast within quad via v_mov_dpp quad_perm (VALU pipe,
// ctrl is a compile-time literal -> K blocks are macro-expanded).
#define QB(v, K) __int_as_float(__builtin_amdgcn_mov_dpp(__float_as_int(v), (K) * 0x55, 0xF, 0xF, 0))

#define IST(Kc, IM, WOFF, S1, S2) { \
  float _xa = QB(Xa[(IM) >> 2][(IM) & 3], Kc); \
  float _xb = QB(Xb[(IM) >> 2][(IM) & 3], Kc); \
  v4f _xav = {_xa, _xa, _xa, _xa}; \
  v4f _xbv = {_xb, _xb, _xb, _xb}; \
  (void)_xav; (void)_xbv; \
  const v4f* _w = (const v4f*)(wbB + ((WOFF) + (Kc) * 16 + (IM)) * 256); \
  _Pragma("unroll") \
  for (int _e = 0; _e < 4; ++_e) { \
    v4f _wv = _w[_e]; \
    acc1[_e] = __builtin_elementwise_fma(S1, _wv, acc1[_e]); \
    acc2[_e] = __builtin_elementwise_fma(S2, _wv, acc2[_e]); \
  } }

#define PH(Kc, WOFF, S1, S2) \
  _Pragma("unroll") \
  for (int _im = 0; _im < 16; ++_im) { IST(Kc, _im, WOFF, S1, S2) }

#define PSTEP(Kc, HF) { \
  float _xp = QB((HF) ? P2y : P2x, Kc); \
  v4f _xpv = {_xp, _xp, _xp, _xp}; \
  const v4f* _w = (const v4f*)(wbB + (128 + (Kc) * 2 + (HF)) * 256); \
  _Pragma("unroll") \
  for (int _e = 0; _e < 4; ++_e) { \
    v4f _wv = _w[_e]; \
    acc1[_e] = __builtin_elementwise_fma(_xpv, _wv, acc1[_e]); \
    acc2[_e] = __builtin_elementwise_fma(_xpv, _wv, acc2[_e]); \
  } }

#define L2B(Kc) \
  _Pragma("unroll") \
  for (int _r = 0; _r < 16; ++_r) { \
    float _h1 = QB(acc1[(_r) >> 2][(_r) & 3], Kc); \
    float _h2 = QB(acc2[(_r) >> 2][(_r) & 3], Kc); \
    v4f _w2 = *(const v4f*)(WB + 137 * 64 + ((Kc) * 16 + _r) * 4); \
    v4f _h1v = {_h1, _h1, _h1, _h1}; \
    v4f _h2v = {_h2, _h2, _h2, _h2}; \
    l1 = __builtin_elementwise_fma(_h1v, _w2, l1); \
    l2 = __builtin_elementwise_fma(_h2v, _w2, l2); \
  }

__global__ __launch_bounds__(256) void router5_k(
    const float* __restrict__ a, const float* __restrict__ b,
    const float* __restrict__ pos, const float* __restrict__ RW,
    unsigned char* __restrict__ r1, unsigned char* __restrict__ r2) {
  __shared__ float WB[142 * 64];
  int tid = threadIdx.x, wave = tid >> 6, lane = tid & 63;
  for (int it = 0; it < 9; it++) {           // 2272 16B chunks
    int cb = it * 256 + wave * 64;
    if (cb < 2272) {
      int chunk = cb + lane;
      if (chunk < 2272) gload_lds16(RW + chunk * 4, (char*)WB + cb * 16);
    }
  }
  __syncthreads();
  int s4 = lane >> 2, jq = lane & 3;
  const char* wbB = (const char*)WB + jq * 64;     // this lane's 16-channel slice
  v4f br2v = *(const v4f*)(WB + 141 * 64);
  int sbase = blockIdx.x * 128 + wave * 32 + s4;   // wave owns 32 samples, 2 passes

  for (int p = 0; p < 2; ++p) {
    int s = sbase + p * 16;
    // coalesced: per wave-instruction the 64 lanes cover a contiguous 4KB span
    v4f Xa[4], Xb[4];
    const v4f* ap = (const v4f*)(a + (size_t)s * 64 + jq * 16);
    const v4f* bp = (const v4f*)(b + (size_t)s * 64 + jq * 16);
    #pragma unroll
    for (int e = 0; e < 4; e++) { Xa[e] = ap[e]; Xb[e] = bp[e]; }
    const float* pp = pos + (size_t)s * 8 + jq * 2;
    float P2x = pp[0], P2y = pp[1];

    v4f acc1[4], acc2[4];
    #pragma unroll
    for (int e = 0; e < 4; e++) {
      v4f bi = *(const v4f*)(WB + 136 * 64 + jq * 16 + e * 4);
      acc1[e] = bi; acc2[e] = bi;
    }
    // phase 1: rows 0..63  — acc1 += a_i*W[i], acc2 += b_i*W[i]  (i ascending)
    PH(0, 0, _xav, _xbv) PH(1, 0, _xav, _xbv) PH(2, 0, _xav, _xbv) PH(3, 0, _xav, _xbv)
    // phase 2: rows 64..127 — acc1 += b_i*W[64+i], acc2 += a_i*W[64+i]
    PH(0, 64, _xbv, _xav) PH(1, 64, _xbv, _xav) PH(2, 64, _xbv, _xav) PH(3, 64, _xbv, _xav)
    // pos rows 128..135 (same multiplier both routings)
    PSTEP(0, 0) PSTEP(0, 1) PSTEP(1, 0) PSTEP(1, 1)
    PSTEP(2, 0) PSTEP(2, 1) PSTEP(3, 0) PSTEP(3, 1)
    // gelu in place
    #pragma unroll
    for (int e = 0; e < 4; e++) {
      #pragma unroll
      for (int c = 0; c < 4; c++) {
        acc1[e][c] = gelu_f(acc1[e][c]);
        acc2[e][c] = gelu_f(acc2[e][c]);
      }
    }
    // layer 2: all 4 quad-lanes redundantly compute the full ordered sum (j asc)
    v4f l1 = br2v, l2 = br2v;
    L2B(0) L2B(1) L2B(2) L2B(3)

    int idx1 = 0; float b1v = l1[0];
    if (l1[1] > b1v) { b1v = l1[1]; idx1 = 1; }
    if (l1[2] > b1v) { b1v = l1[2]; idx1 = 2; }
    if (l1[3] > b1v) { b1v = l1[3]; idx1 = 3; }
    int idx2 = 0; float b2v = l2[0];
    if (l2[1] > b2v) { b2v = l2[1]; idx2 = 1; }
    if (l2[2] > b2v) { b2v = l2[2]; idx2 = 2; }
    if (l2[3] > b2v) { b2v = l2[3]; idx2 = 3; }
    if (jq == 0) {
      r1[s] = (unsigned char)idx1;
      r2[s] = (unsigned char)idx2;
    }
  }
}

// ---------------- K3: experts, LDS-phased weights + MFMA (unchanged) -------------
__global__ __launch_bounds__(256) void expert2_k(
    const float* __restrict__ a, const float* __restrict__ b,
    const short* __restrict__ W1s, const short* __restrict__ W2s,
    const float* __restrict__ b1, const float* __restrict__ b2,
    const unsigned char* __restrict__ r1, const unsigned char* __restrict__ r2,
    float* __restrict__ out) {
  __shared__ short LB[24576];  // 48KB; overlaid: pair-frag staging (32KB) then weights
  int tid = threadIdx.x;
  int wave = tid >> 6, lane = tid & 63;
  int q = lane >> 4, sm = lane & 15;
  int s0 = blockIdx.x * 128;

  // stage pair^T B-fragments for both groups (lane-linear 16B slots)
  #pragma unroll
  for (int r = 0; r < 8; r++) {
    int slot = r * 256 + tid;                 // 2048 slots
    int g = slot >> 10, sg = slot & 1023;
    int f = sg >> 6, l = sg & 63;
    int sgrp = f >> 2, kb = f & 3;
    int s = s0 + g * 64 + sgrp * 16 + (l & 15);
    int k = kb * 32 + (l >> 4) * 8;
    const float* src = (k < 64) ? (a + s * 64 + k) : (b + s * 64 + (k - 64));
    acc_t v0 = *(const acc_t*)(src);
    acc_t v1 = *(const acc_t*)(src + 4);
    i32x4_t pk;
    pk[0] = (int)pk2bf(v0[0], v0[1]);
    pk[1] = (int)pk2bf(v0[2], v0[3]);
    pk[2] = (int)pk2bf(v1[0], v1[1]);
    pk[3] = (int)pk2bf(v1[2], v1[3]);
    *(i32x4_t*)(&LB[slot * 8]) = pk;
  }
  __syncthreads();
  bfrag_t bfrag[2][4];
  #pragma unroll
  for (int g = 0; g < 2; g++)
    #pragma unroll
    for (int kb = 0; kb < 4; kb++)
      bfrag[g][kb] = *(const bfrag_t*)(&LB[((g * 16 + wave * 4 + kb) * 64 + lane) * 8]);

  int sA = s0 + wave * 16 + sm, sB = sA + 64;
  int i1A = (int)r1[sA], i2A = (int)r2[sA];
  int i1B = (int)r1[sB], i2B = (int)r2[sB];
  __syncthreads();   // all frag reads done before weights overwrite LB

  acc_t zero = {0.f, 0.f, 0.f, 0.f};
  acc_t o1[2][4], o2[2][4];
  #pragma unroll
  for (int g = 0; g < 2; g++)
    #pragma unroll
    for (int i = 0; i < 4; i++) { o1[g][i] = zero; o2[g][i] = zero; }

  int vb[4];
  #pragma unroll
  for (int kb = 0; kb < 4; kb++) vb[kb] = sm * 256 + (((kb * 4 + q) ^ sm) * 16);
  int addr0 = (((q & 1) * 2) * 16 + sm) * 4;
  int addr1 = addr0 + 64;
  bool hi = (q >> 1) != 0;

  for (int t = 0; t < 4; t++) {
    // stage expert t: W1s 32KB (2048 chunks) + W2s 16KB (1024 chunks) = 3072 chunks
    #pragma unroll
    for (int it = 0; it < 12; it++) {
      int cb = it * 256 + wave * 64;          // wave-uniform base
      int chunk = cb + lane;
      const short* gsrc = (chunk < 2048) ? (W1s + t * 16384 + chunk * 8)
                                         : (W2s + t * 8192 + (chunk - 2048) * 8);
      gload_lds16(gsrc, (char*)LB + cb * 16);
    }
    __syncthreads();
    #pragma unroll
    for (int g = 0; g < 2; g++) {
      // layer 1: h^T
      unsigned int hp[8][2];
      #pragma unroll
      for (int mt = 0; mt < 8; mt++) {
        acc_t c = zero;
        #pragma unroll
        for (int kb = 0; kb < 4; kb++) {
          bfrag_t A = *(const bfrag_t*)((const char*)LB + mt * 4096 + vb[kb]);
          c = __builtin_amdgcn_mfma_f32_16x16x32_bf16(A, bfrag[g][kb], c, 0, 0, 0);
        }
        acc_t bv = *(const acc_t*)(b1 + t * 128 + mt * 16 + q * 4);
        float g0 = gelu_f(c[0] + bv[0]);
        float g1 = gelu_f(c[1] + bv[1]);
        float g2 = gelu_f(c[2] + bv[2]);
        float g3 = gelu_f(c[3] + bv[3]);
        hp[mt][0] = pk2bf(g0, g1);
        hp[mt][1] = pk2bf(g2, g3);
      }
      // redistribute h^T C-frags -> layer-2 B-frags (wave-local bpermute)
      bfrag_t b2f[4];
      #pragma unroll
      for (int kb2 = 0; kb2 < 4; kb2++) {
        int p00 = __builtin_amdgcn_ds_bpermute(addr0, (int)hp[2 * kb2][0]);
        int p01 = __builtin_amdgcn_ds_bpermute(addr0, (int)hp[2 * kb2][1]);
        int p10 = __builtin_amdgcn_ds_bpermute(addr1, (int)hp[2 * kb2][0]);
        int p11 = __builtin_amdgcn_ds_bpermute(addr1, (int)hp[2 * kb2][1]);
        int q00 = __builtin_amdgcn_ds_bpermute(addr0, (int)hp[2 * kb2 + 1][0]);
        int q01 = __builtin_amdgcn_ds_bpermute(addr0, (int)hp[2 * kb2 + 1][1]);
        int q10 = __builtin_amdgcn_ds_bpermute(addr1, (int)hp[2 * kb2 + 1][0]);
        int q11 = __builtin_amdgcn_ds_bpermute(addr1, (int)hp[2 * kb2 + 1][1]);
        i32x4_t w;
        w[0] = hi ? q00 : p00;
        w[1] = hi ? q01 : p01;
        w[2] = hi ? q10 : p10;
        w[3] = hi ? q11 : p11;
        b2f[kb2] = __builtin_bit_cast(bfrag_t, w);
      }
      // layer 2 + per-sample select
      int i1g = g ? i1B : i1A;
      int i2g = g ? i2B : i2A;
      #pragma unroll
      for (int mt2 = 0; mt2 < 4; mt2++) {
        acc_t c = zero;
        #pragma unroll
        for (int kb2 = 0; kb2 < 4; kb2++) {
          bfrag_t A = *(const bfrag_t*)((const char*)LB + 32768 + mt2 * 4096 + vb[kb2]);
          c = __builtin_amdgcn_mfma_f32_16x16x32_bf16(A, b2f[kb2], c, 0, 0, 0);
        }
        acc_t bv = *(const acc_t*)(b2 + t * 64 + mt2 * 16 + q * 4);
        c[0] += bv[0]; c[1] += bv[1]; c[2] += bv[2]; c[3] += bv[3];
        o1[g][mt2] = (i1g == t) ? c : o1[g][mt2];
        o2[g][mt2] = (i2g == t) ? c : o2[g][mt2];
      }
    }
    __syncthreads();   // compute done before next phase overwrites LB
  }
  #pragma unroll
  for (int g = 0; g < 2; g++) {
    int so = g ? sB : sA;
    float* p1 = out + so * 64 + q * 4;
    float* p2 = out + (size_t)B_N * 64 + so * 64 + q * 4;
    #pragma unroll
    for (int mt2 = 0; mt2 < 4; mt2++) {
      *(acc_t*)(p1 + mt2 * 16) = o1[g][mt2];
      *(acc_t*)(p2 + mt2 * 16) = o2[g][mt2];
    }
  }
}

extern "C" void kernel_launch(void* const* d_in, const int* in_sizes, int n_in,
                              void* d_out, int out_size, void* d_ws, size_t ws_size,
                              hipStream_t stream) {
  const float* a   = (const float*)d_in[0];
  const float* bv  = (const float*)d_in[1];
  const float* pos = (const float*)d_in[2];
  const float* Wr1 = (const float*)d_in[3];
  const float* br1 = (const float*)d_in[4];
  const float* Wr2 = (const float*)d_in[5];
  const float* br2 = (const float*)d_in[6];
  const float* W1  = (const float*)d_in[7];
  const float* b1  = (const float*)d_in[8];
  const float* W2  = (const float*)d_in[9];
  const float* b2  = (const float*)d_in[10];
  float* out = (float*)d_out;

  // ws layout (BYTES): r1 [0,131072) r2 [131072,262144) RW [262144,298496)
  // W1s [298496,429568)  W2s [429568,495104)
  unsigned char* r1 = (unsigned char*)d_ws;
  unsigned char* r2 = r1 + B_N;
  float* RW  = (float*)((char*)d_ws + 262144);
  short* W1s = (short*)((char*)d_ws + 298496);
  short* W2s = (short*)((char*)d_ws + 429568);

  prepack2_k<<<64, 256, 0, stream>>>(Wr1, br1, Wr2, br2, W1, W2, RW, W1s, W2s);
  router5_k<<<B_N / 128, 256, 0, stream>>>(a, bv, pos, RW, r1, r2);
  expert2_k<<<B_N / 128, 256, 0, stream>>>(a, bv, W1s, W2s, b1, b2, r1, r2, out);
}

// Round 2
// 271.647 us; speedup vs baseline: 6.0250x; 6.0250x over previous
//
#include <hip/hip_runtime.h>

#define B_N 131072

using bfrag_t = __attribute__((ext_vector_type(8))) short;  // 8 bf16 (MFMA A/B frag)
using acc_t   = __attribute__((ext_vector_type(4))) float;  // 4 fp32 (MFMA C/D frag)
using v4f     = __attribute__((ext_vector_type(4))) float;
using i32x4_t = __attribute__((ext_vector_type(4))) int;

__device__ __forceinline__ unsigned short f2bf(float f) {
  unsigned int u = __float_as_uint(f);
  u += 0x7FFFu + ((u >> 16) & 1u);   // RNE
  return (unsigned short)(u >> 16);
}

__device__ __forceinline__ unsigned int pk2bf(float x, float y) {
  return (unsigned int)f2bf(x) | ((unsigned int)f2bf(y) << 16);
}

// async global->LDS, 16B per lane; lds base must be wave-uniform (lane-linear dest)
__device__ __forceinline__ void gload_lds16(const void* g, void* l) {
  __builtin_amdgcn_global_load_lds((const __attribute__((address_space(1))) void*)g,
                                   (__attribute__((address_space(3))) void*)l, 16, 0, 0);
}

// exact GELU: 0.5x(1+erf(x/sqrt2)); erf via Abramowitz-Stegun 7.1.26, |eps|<=1.5e-7
__device__ __forceinline__ float gelu_f(float x) {
  float ax = fabsf(x) * 0.70710678118654752f;
  float t  = __builtin_amdgcn_rcpf(fmaf(0.3275911f, ax, 1.0f));
  float p  = fmaf(1.061405429f, t, -1.453152027f);
  p = fmaf(p, t, 1.421413741f);
  p = fmaf(p, t, -0.284496736f);
  p = fmaf(p, t, 0.254829592f);
  p = p * t;
  float e  = __expf(-ax * ax);
  float er = fmaf(-p, e, 1.0f);
  er = (x < 0.0f) ? -er : er;
  return 0.5f * x * (1.0f + er);
}

// ---------------- K1: prepack (unchanged from round-0 281us version) ----------------
__global__ __launch_bounds__(256) void prepack2_k(
    const float* __restrict__ Wr1, const float* __restrict__ br1,
    const float* __restrict__ Wr2, const float* __restrict__ br2,
    const float* __restrict__ W1, const float* __restrict__ W2,
    float* __restrict__ RW, short* __restrict__ W1s, short* __restrict__ W2s) {
  int gt = blockIdx.x * 256 + threadIdx.x;   // grid 64 -> 16384 threads
  for (int idx = gt; idx < 142 * 64; idx += 16384) {
    int row = idx >> 6, j = idx & 63; float val;
    if (row < 136)      val = Wr1[row * 64 + j];
    else if (row == 136) val = br1[j];
    else if (row < 141) val = Wr2[(row - 137) * 64 + j];
    else                val = (j < 4) ? br2[j] : 0.0f;
    RW[idx] = val;
  }
  for (int ch = gt; ch < 8192; ch += 16384) {  // W1: (4,128,128) [t][k][n]
    int t = ch >> 11, r = (ch >> 4) & 127, c = ch & 15;
    const float* src = W1 + t * 16384 + r;     // stride 128 over k
    short* dst = W1s + (t * 128 + r) * 128 + ((c ^ (r & 15)) * 8);
    #pragma unroll
    for (int m = 0; m < 8; m++) dst[m] = (short)f2bf(src[(c * 8 + m) * 128]);
  }
  for (int ch = gt; ch < 4096; ch += 16384) {  // W2: (4,128,64) [t][k][d]
    int t = ch >> 10, d = (ch >> 4) & 63, c = ch & 15;
    const float* src = W2 + t * 8192 + d;      // stride 64 over k
    short* dst = W2s + (t * 64 + d) * 128 + ((c ^ (d & 15)) * 8);
    #pragma unroll
    for (int m = 0; m < 8; m++) dst[m] = (short)f2bf(src[(c * 8 + m) * 64]);
  }
}

// ---------------- K2: router v6 — LDS-staged x, runtime loops, exact fp32 order ----
// Block = 256 threads = 64 samples; quad per sample: sq = tid>>2, jq = tid&3 owns
// channels jq*16..jq*16+15 (acc = 32 VGPRs). x staged ONCE, coalesced, to LDS
// transposed X[row][sample] stride 65 (65 mod 32 == 1: writes 2-way (free), reads
// conflict-free, quad-same-address = broadcast). Per channel j the fp32 fma chain
// is IDENTICAL to the round-0 passing kernel: br1 -> a_i*W[i] (i asc) ->
// b_i*W[64+i] -> pos (acc1); b_i / a_i swapped (acc2); gelu; br2 + h_j asc.
// No register-held x, no full unroll, no dynamic register indexing (round-1 lesson).
__global__ __launch_bounds__(256) void router6_k(
    const float* __restrict__ a, const float* __restrict__ b,
    const float* __restrict__ pos, const float* __restrict__ RW,
    unsigned char* __restrict__ r1, unsigned char* __restrict__ r2) {
  __shared__ float SB[17928];            // 71712 B -> 2 blocks/CU
  const int XA = 9088, XB = 13248, PP = 17408;   // float offsets
  int tid = threadIdx.x, wave = tid >> 6, lane = tid & 63;
  int s0 = blockIdx.x * 64;

  // WB: rows 0-135 Wr1, 136 br1, 137-140 Wr2 flat, 141 br2 (2272 16B chunks)
  for (int it = 0; it < 9; it++) {
    int cb = it * 256 + wave * 64;       // wave-uniform lds base
    if (cb < 2272) {
      int chunk = cb + lane;
      if (chunk < 2272) gload_lds16(RW + chunk * 4, (char*)SB + cb * 16);
    }
  }
  // X: coalesced v4f global loads (1KB/wave-instr), transpose-store to LDS
  #pragma unroll
  for (int it = 0; it < 4; it++) {
    int idx = it * 256 + tid;            // 1024 = 64 samples x 16 chunks
    int s = idx >> 4, c = idx & 15;
    v4f va = *(const v4f*)(a + (size_t)(s0 + s) * 64 + c * 4);
    v4f vb = *(const v4f*)(b + (size_t)(s0 + s) * 64 + c * 4);
    #pragma unroll
    for (int k = 0; k < 4; k++) {
      SB[XA + (c * 4 + k) * 65 + s] = va[k];
      SB[XB + (c * 4 + k) * 65 + s] = vb[k];
    }
  }
  #pragma unroll
  for (int r = 0; r < 2; r++) {
    int idx = r * 256 + tid;             // 512 = 64 samples x 8
    int s = idx >> 3, c = idx & 7;
    SB[PP + c * 65 + s] = pos[(size_t)(s0 + s) * 8 + c];
  }
  __syncthreads();

  int sq = tid >> 2, jq = tid & 3;
  v4f acc1[4], acc2[4];
  #pragma unroll
  for (int e = 0; e < 4; e++) {
    v4f bi = *(const v4f*)(SB + 136 * 64 + jq * 16 + e * 4);
    acc1[e] = bi; acc2[e] = bi;
  }
  // rows 0..63: acc1 += a_i*W[i], acc2 += b_i*W[i]  (i ascending)
  #pragma unroll 4
  for (int i = 0; i < 64; ++i) {
    float xa = SB[XA + i * 65 + sq];
    float xb = SB[XB + i * 65 + sq];
    const v4f* w = (const v4f*)(SB + i * 64 + jq * 16);
    v4f xav = {xa, xa, xa, xa}, xbv = {xb, xb, xb, xb};
    #pragma unroll
    for (int e = 0; e < 4; e++) {
      v4f wv = w[e];
      acc1[e] = __builtin_elementwise_fma(xav, wv, acc1[e]);
      acc2[e] = __builtin_elementwise_fma(xbv, wv, acc2[e]);
    }
  }
  // rows 64..127: acc1 += b_i*W[64+i], acc2 += a_i*W[64+i]
  #pragma unroll 4
  for (int i = 0; i < 64; ++i) {
    float xa = SB[XA + i * 65 + sq];
    float xb = SB[XB + i * 65 + sq];
    const v4f* w = (const v4f*)(SB + (64 + i) * 64 + jq * 16);
    v4f xav = {xa, xa, xa, xa}, xbv = {xb, xb, xb, xb};
    #pragma unroll
    for (int e = 0; e < 4; e++) {
      v4f wv = w[e];
      acc1[e] = __builtin_elementwise_fma(xbv, wv, acc1[e]);
      acc2[e] = __builtin_elementwise_fma(xav, wv, acc2[e]);
    }
  }
  // pos rows 128..135 (same multiplier both routings)
  #pragma unroll 2
  for (int i = 0; i < 8; ++i) {
    float p = SB[PP + i * 65 + sq];
    const v4f* w = (const v4f*)(SB + (128 + i) * 64 + jq * 16);
    v4f pv = {p, p, p, p};
    #pragma unroll
    for (int e = 0; e < 4; e++) {
      v4f wv = w[e];
      acc1[e] = __builtin_elementwise_fma(pv, wv, acc1[e]);
      acc2[e] = __builtin_elementwise_fma(pv, wv, acc2[e]);
    }
  }
  // gelu in place
  #pragma unroll
  for (int e = 0; e < 4; e++) {
    #pragma unroll
    for (int c = 0; c < 4; c++) {
      acc1[e][c] = gelu_f(acc1[e][c]);
      acc2[e][c] = gelu_f(acc2[e][c]);
    }
  }
  __syncthreads();   // all X/P reads done before h overwrites the X region
  // h -> LDS, transposed [j][sample], same stride-65 layout (reuses XA/XB regions);
  // column sq is quad-private: writes/reads stay within one wave (lockstep-safe),
  // barrier below is belt-and-braces.
  #pragma unroll
  for (int e = 0; e < 4; e++) {
    #pragma unroll
    for (int c = 0; c < 4; c++) {
      int j = jq * 16 + e * 4 + c;
      SB[XA + j * 65 + sq] = acc1[e][c];
      SB[XB + j * 65 + sq] = acc2[e][c];
    }
  }
  __syncthreads();
  // layer 2: ordered sum j = 0..63 (exact round-0 sequence), all quad lanes redundant
  v4f l1 = *(const v4f*)(SB + 141 * 64);
  v4f l2 = l1;
  #pragma unroll 4
  for (int j = 0; j < 64; ++j) {
    float h1 = SB[XA + j * 65 + sq];
    float h2 = SB[XB + j * 65 + sq];
    v4f w2 = *(const v4f*)(SB + 137 * 64 + j * 4);
    v4f h1v = {h1, h1, h1, h1}, h2v = {h2, h2, h2, h2};
    l1 = __builtin_elementwise_fma(h1v, w2, l1);
    l2 = __builtin_elementwise_fma(h2v, w2, l2);
  }
  int idx1 = 0; float b1v = l1[0];
  if (l1[1] > b1v) { b1v = l1[1]; idx1 = 1; }
  if (l1[2] > b1v) { b1v = l1[2]; idx1 = 2; }
  if (l1[3] > b1v) { b1v = l1[3]; idx1 = 3; }
  int idx2 = 0; float b2v = l2[0];
  if (l2[1] > b2v) { b2v = l2[1]; idx2 = 1; }
  if (l2[2] > b2v) { b2v = l2[2]; idx2 = 2; }
  if (l2[3] > b2v) { b2v = l2[3]; idx2 = 3; }
  if (jq == 0) {
    r1[s0 + sq] = (unsigned char)idx1;
    r2[s0 + sq] = (unsigned char)idx2;
  }
}

// ---------------- K3: experts (unchanged from round-0 281us version) -------------
__global__ __launch_bounds__(256) void expert2_k(
    const float* __restrict__ a, const float* __restrict__ b,
    const short* __restrict__ W1s, const short* __restrict__ W2s,
    const float* __restrict__ b1, const float* __restrict__ b2,
    const unsigned char* __restrict__ r1, const unsigned char* __restrict__ r2,
    float* __restrict__ out) {
  __shared__ short LB[24576];  // 48KB; overlaid: pair-frag staging (32KB) then weights
  int tid = threadIdx.x;
  int wave = tid >> 6, lane = tid & 63;
  int q = lane >> 4, sm = lane & 15;
  int s0 = blockIdx.x * 128;

  // stage pair^T B-fragments for both groups (lane-linear 16B slots)
  #pragma unroll
  for (int r = 0; r < 8; r++) {
    int slot = r * 256 + tid;                 // 2048 slots
    int g = slot >> 10, sg = slot & 1023;
    int f = sg >> 6, l = sg & 63;
    int sgrp = f >> 2, kb = f & 3;
    int s = s0 + g * 64 + sgrp * 16 + (l & 15);
    int k = kb * 32 + (l >> 4) * 8;
    const float* src = (k < 64) ? (a + s * 64 + k) : (b + s * 64 + (k - 64));
    acc_t v0 = *(const acc_t*)(src);
    acc_t v1 = *(const acc_t*)(src + 4);
    i32x4_t pk;
    pk[0] = (int)pk2bf(v0[0], v0[1]);
    pk[1] = (int)pk2bf(v0[2], v0[3]);
    pk[2] = (int)pk2bf(v1[0], v1[1]);
    pk[3] = (int)pk2bf(v1[2], v1[3]);
    *(i32x4_t*)(&LB[slot * 8]) = pk;
  }
  __syncthreads();
  bfrag_t bfrag[2][4];
  #pragma unroll
  for (int g = 0; g < 2; g++)
    #pragma unroll
    for (int kb = 0; kb < 4; kb++)
      bfrag[g][kb] = *(const bfrag_t*)(&LB[((g * 16 + wave * 4 + kb) * 64 + lane) * 8]);

  int sA = s0 + wave * 16 + sm, sB = sA + 64;
  int i1A = (int)r1[sA], i2A = (int)r2[sA];
  int i1B = (int)r1[sB], i2B = (int)r2[sB];
  __syncthreads();   // all frag reads done before weights overwrite LB

  acc_t zero = {0.f, 0.f, 0.f, 0.f};
  acc_t o1[2][4], o2[2][4];
  #pragma unroll
  for (int g = 0; g < 2; g++)
    #pragma unroll
    for (int i = 0; i < 4; i++) { o1[g][i] = zero; o2[g][i] = zero; }

  int vb[4];
  #pragma unroll
  for (int kb = 0; kb < 4; kb++) vb[kb] = sm * 256 + (((kb * 4 + q) ^ sm) * 16);
  int addr0 = (((q & 1) * 2) * 16 + sm) * 4;
  int addr1 = addr0 + 64;
  bool hi = (q >> 1) != 0;

  for (int t = 0; t < 4; t++) {
    // stage expert t: W1s 32KB (2048 chunks) + W2s 16KB (1024 chunks) = 3072 chunks
    #pragma unroll
    for (int it = 0; it < 12; it++) {
      int cb = it * 256 + wave * 64;          // wave-uniform base
      int chunk = cb + lane;
      const short* gsrc = (chunk < 2048) ? (W1s + t * 16384 + chunk * 8)
                                         : (W2s + t * 8192 + (chunk - 2048) * 8);
      gload_lds16(gsrc, (char*)LB + cb * 16);
    }
    __syncthreads();
    #pragma unroll
    for (int g = 0; g < 2; g++) {
      // layer 1: h^T
      unsigned int hp[8][2];
      #pragma unroll
      for (int mt = 0; mt < 8; mt++) {
        acc_t c = zero;
        #pragma unroll
        for (int kb = 0; kb < 4; kb++) {
          bfrag_t A = *(const bfrag_t*)((const char*)LB + mt * 4096 + vb[kb]);
          c = __builtin_amdgcn_mfma_f32_16x16x32_bf16(A, bfrag[g][kb], c, 0, 0, 0);
        }
        acc_t bv = *(const acc_t*)(b1 + t * 128 + mt * 16 + q * 4);
        float g0 = gelu_f(c[0] + bv[0]);
        float g1 = gelu_f(c[1] + bv[1]);
        float g2 = gelu_f(c[2] + bv[2]);
        float g3 = gelu_f(c[3] + bv[3]);
        hp[mt][0] = pk2bf(g0, g1);
        hp[mt][1] = pk2bf(g2, g3);
      }
      // redistribute h^T C-frags -> layer-2 B-frags (wave-local bpermute)
      bfrag_t b2f[4];
      #pragma unroll
      for (int kb2 = 0; kb2 < 4; kb2++) {
        int p00 = __builtin_amdgcn_ds_bpermute(addr0, (int)hp[2 * kb2][0]);
        int p01 = __builtin_amdgcn_ds_bpermute(addr0, (int)hp[2 * kb2][1]);
        int p10 = __builtin_amdgcn_ds_bpermute(addr1, (int)hp[2 * kb2][0]);
        int p11 = __builtin_amdgcn_ds_bpermute(addr1, (int)hp[2 * kb2][1]);
        int q00 = __builtin_amdgcn_ds_bpermute(addr0, (int)hp[2 * kb2 + 1][0]);
        int q01 = __builtin_amdgcn_ds_bpermute(addr0, (int)hp[2 * kb2 + 1][1]);
        int q10 = __builtin_amdgcn_ds_bpermute(addr1, (int)hp[2 * kb2 + 1][0]);
        int q11 = __builtin_amdgcn_ds_bpermute(addr1, (int)hp[2 * kb2 + 1][1]);
        i32x4_t w;
        w[0] = hi ? q00 : p00;
        w[1] = hi ? q01 : p01;
        w[2] = hi ? q10 : p10;
        w[3] = hi ? q11 : p11;
        b2f[kb2] = __builtin_bit_cast(bfrag_t, w);
      }
      // layer 2 + per-sample select
      int i1g = g ? i1B : i1A;
      int i2g = g ? i2B : i2A;
      #pragma unroll
      for (int mt2 = 0; mt2 < 4; mt2++) {
        acc_t c = zero;
        #pragma unroll
        for (int kb2 = 0; kb2 < 4; kb2++) {
          bfrag_t A = *(const bfrag_t*)((const char*)LB + 32768 + mt2 * 4096 + vb[kb2]);
          c = __builtin_amdgcn_mfma_f32_16x16x32_bf16(A, b2f[kb2], c, 0, 0, 0);
        }
        acc_t bv = *(const acc_t*)(b2 + t * 64 + mt2 * 16 + q * 4);
        c[0] += bv[0]; c[1] += bv[1]; c[2] += bv[2]; c[3] += bv[3];
        o1[g][mt2] = (i1g == t) ? c : o1[g][mt2];
        o2[g][mt2] = (i2g == t) ? c : o2[g][mt2];
      }
    }
    __syncthreads();   // compute done before next phase overwrites LB
  }
  #pragma unroll
  for (int g = 0; g < 2; g++) {
    int so = g ? sB : sA;
    float* p1 = out + so * 64 + q * 4;
    float* p2 = out + (size_t)B_N * 64 + so * 64 + q * 4;
    #pragma unroll
    for (int mt2 = 0; mt2 < 4; mt2++) {
      *(acc_t*)(p1 + mt2 * 16) = o1[g][mt2];
      *(acc_t*)(p2 + mt2 * 16) = o2[g][mt2];
    }
  }
}

extern "C" void kernel_launch(void* const* d_in, const int* in_sizes, int n_in,
                              void* d_out, int out_size, void* d_ws, size_t ws_size,
                              hipStream_t stream) {
  const float* a   = (const float*)d_in[0];
  const float* bv  = (const float*)d_in[1];
  const float* pos = (const float*)d_in[2];
  const float* Wr1 = (const float*)d_in[3];
  const float* br1 = (const float*)d_in[4];
  const float* Wr2 = (const float*)d_in[5];
  const float* br2 = (const float*)d_in[6];
  const float* W1  = (const float*)d_in[7];
  const float* b1  = (const float*)d_in[8];
  const float* W2  = (const float*)d_in[9];
  const float* b2  = (const float*)d_in[10];
  float* out = (float*)d_out;

  // ws layout (BYTES): r1 [0,131072) r2 [131072,262144) RW [262144,298496)
  // W1s [298496,429568)  W2s [429568,495104)
  unsigned char* r1 = (unsigned char*)d_ws;
  unsigned char* r2 = r1 + B_N;
  float* RW  = (float*)((char*)d_ws + 262144);
  short* W1s = (short*)((char*)d_ws + 298496);
  short* W2s = (short*)((char*)d_ws + 429568);

  prepack2_k<<<64, 256, 0, stream>>>(Wr1, br1, Wr2, br2, W1, W2, RW, W1s, W2s);
  router6_k<<<B_N / 64, 256, 0, stream>>>(a, bv, pos, RW, r1, r2);
  expert2_k<<<B_N / 128, 256, 0, stream>>>(a, bv, W1s, W2s, b1, b2, r1, r2, out);
}

// Round 3
// 254.216 us; speedup vs baseline: 6.4381x; 1.0686x over previous
//
#include <hip/hip_runtime.h>

#define B_N 131072

using bfrag_t = __attribute__((ext_vector_type(8))) short;  // 8 bf16 (MFMA A/B frag)
using acc_t   = __attribute__((ext_vector_type(4))) float;  // 4 fp32 (MFMA C/D frag)
using v4f     = __attribute__((ext_vector_type(4))) float;
using i32x4_t = __attribute__((ext_vector_type(4))) int;

__device__ __forceinline__ unsigned short f2bf(float f) {
  unsigned int u = __float_as_uint(f);
  u += 0x7FFFu + ((u >> 16) & 1u);   // RNE
  return (unsigned short)(u >> 16);
}

__device__ __forceinline__ unsigned int pk2bf(float x, float y) {
  return (unsigned int)f2bf(x) | ((unsigned int)f2bf(y) << 16);
}

// async global->LDS, 16B per lane; lds base must be wave-uniform (lane-linear dest)
__device__ __forceinline__ void gload_lds16(const void* g, void* l) {
  __builtin_amdgcn_global_load_lds((const __attribute__((address_space(1))) void*)g,
                                   (__attribute__((address_space(3))) void*)l, 16, 0, 0);
}

// exact GELU: 0.5x(1+erf(x/sqrt2)); erf via Abramowitz-Stegun 7.1.26, |eps|<=1.5e-7
__device__ __forceinline__ float gelu_f(float x) {
  float ax = fabsf(x) * 0.70710678118654752f;
  float t  = __builtin_amdgcn_rcpf(fmaf(0.3275911f, ax, 1.0f));
  float p  = fmaf(1.061405429f, t, -1.453152027f);
  p = fmaf(p, t, 1.421413741f);
  p = fmaf(p, t, -0.284496736f);
  p = fmaf(p, t, 0.254829592f);
  p = p * t;
  float e  = __expf(-ax * ax);
  float er = fmaf(-p, e, 1.0f);
  er = (x < 0.0f) ? -er : er;
  return 0.5f * x * (1.0f + er);
}

// ---------------- K1: prepack (round-0 version + counter zeroing) ----------------
__global__ __launch_bounds__(256) void prepack2_k(
    const float* __restrict__ Wr1, const float* __restrict__ br1,
    const float* __restrict__ Wr2, const float* __restrict__ br2,
    const float* __restrict__ W1, const float* __restrict__ W2,
    float* __restrict__ RW, short* __restrict__ W1s, short* __restrict__ W2s,
    unsigned int* __restrict__ counts) {
  int gt = blockIdx.x * 256 + threadIdx.x;   // grid 64 -> 16384 threads
  if (gt < 4) counts[gt] = 0u;
  for (int idx = gt; idx < 142 * 64; idx += 16384) {
    int row = idx >> 6, j = idx & 63; float val;
    if (row < 136)      val = Wr1[row * 64 + j];
    else if (row == 136) val = br1[j];
    else if (row < 141) val = Wr2[(row - 137) * 64 + j];
    else                val = (j < 4) ? br2[j] : 0.0f;
    RW[idx] = val;
  }
  for (int ch = gt; ch < 8192; ch += 16384) {  // W1: (4,128,128) [t][k][n]
    int t = ch >> 11, r = (ch >> 4) & 127, c = ch & 15;
    const float* src = W1 + t * 16384 + r;     // stride 128 over k
    short* dst = W1s + (t * 128 + r) * 128 + ((c ^ (r & 15)) * 8);
    #pragma unroll
    for (int m = 0; m < 8; m++) dst[m] = (short)f2bf(src[(c * 8 + m) * 128]);
  }
  for (int ch = gt; ch < 4096; ch += 16384) {  // W2: (4,128,64) [t][k][d]
    int t = ch >> 10, d = (ch >> 4) & 63, c = ch & 15;
    const float* src = W2 + t * 8192 + d;      // stride 64 over k
    short* dst = W2s + (t * 64 + d) * 128 + ((c ^ (d & 15)) * 8);
    #pragma unroll
    for (int m = 0; m < 8; m++) dst[m] = (short)f2bf(src[(c * 8 + m) * 64]);
  }
}

// ---------------- K2: router v7 = v6 + per-block expert histogram ----------------
// fp32 fma chain per channel is IDENTICAL to the round-0 passing kernel (argmax
// safety). Adds: LDS histogram of idx1/idx2 -> global counts[4].
__global__ __launch_bounds__(256) void router7_k(
    const float* __restrict__ a, const float* __restrict__ b,
    const float* __restrict__ pos, const float* __restrict__ RW,
    unsigned char* __restrict__ r1, unsigned char* __restrict__ r2,
    unsigned int* __restrict__ gcounts) {
  __shared__ float SB[17928];            // 71712 B -> 2 blocks/CU
  __shared__ unsigned int hcnt[4];
  const int XA = 9088, XB = 13248, PP = 17408;   // float offsets
  int tid = threadIdx.x, wave = tid >> 6, lane = tid & 63;
  int s0 = blockIdx.x * 64;
  if (tid < 4) hcnt[tid] = 0u;

  // WB: rows 0-135 Wr1, 136 br1, 137-140 Wr2 flat, 141 br2 (2272 16B chunks)
  for (int it = 0; it < 9; it++) {
    int cb = it * 256 + wave * 64;       // wave-uniform lds base
    if (cb < 2272) {
      int chunk = cb + lane;
      if (chunk < 2272) gload_lds16(RW + chunk * 4, (char*)SB + cb * 16);
    }
  }
  // X: coalesced v4f global loads, transpose-store to LDS (stride 65)
  #pragma unroll
  for (int it = 0; it < 4; it++) {
    int idx = it * 256 + tid;            // 1024 = 64 samples x 16 chunks
    int s = idx >> 4, c = idx & 15;
    v4f va = *(const v4f*)(a + (size_t)(s0 + s) * 64 + c * 4);
    v4f vb = *(const v4f*)(b + (size_t)(s0 + s) * 64 + c * 4);
    #pragma unroll
    for (int k = 0; k < 4; k++) {
      SB[XA + (c * 4 + k) * 65 + s] = va[k];
      SB[XB + (c * 4 + k) * 65 + s] = vb[k];
    }
  }
  #pragma unroll
  for (int r = 0; r < 2; r++) {
    int idx = r * 256 + tid;             // 512 = 64 samples x 8
    int s = idx >> 3, c = idx & 7;
    SB[PP + c * 65 + s] = pos[(size_t)(s0 + s) * 8 + c];
  }
  __syncthreads();

  int sq = tid >> 2, jq = tid & 3;
  v4f acc1[4], acc2[4];
  #pragma unroll
  for (int e = 0; e < 4; e++) {
    v4f bi = *(const v4f*)(SB + 136 * 64 + jq * 16 + e * 4);
    acc1[e] = bi; acc2[e] = bi;
  }
  // rows 0..63: acc1 += a_i*W[i], acc2 += b_i*W[i]  (i ascending)
  #pragma unroll 4
  for (int i = 0; i < 64; ++i) {
    float xa = SB[XA + i * 65 + sq];
    float xb = SB[XB + i * 65 + sq];
    const v4f* w = (const v4f*)(SB + i * 64 + jq * 16);
    v4f xav = {xa, xa, xa, xa}, xbv = {xb, xb, xb, xb};
    #pragma unroll
    for (int e = 0; e < 4; e++) {
      v4f wv = w[e];
      acc1[e] = __builtin_elementwise_fma(xav, wv, acc1[e]);
      acc2[e] = __builtin_elementwise_fma(xbv, wv, acc2[e]);
    }
  }
  // rows 64..127: acc1 += b_i*W[64+i], acc2 += a_i*W[64+i]
  #pragma unroll 4
  for (int i = 0; i < 64; ++i) {
    float xa = SB[XA + i * 65 + sq];
    float xb = SB[XB + i * 65 + sq];
    const v4f* w = (const v4f*)(SB + (64 + i) * 64 + jq * 16);
    v4f xav = {xa, xa, xa, xa}, xbv = {xb, xb, xb, xb};
    #pragma unroll
    for (int e = 0; e < 4; e++) {
      v4f wv = w[e];
      acc1[e] = __builtin_elementwise_fma(xbv, wv, acc1[e]);
      acc2[e] = __builtin_elementwise_fma(xav, wv, acc2[e]);
    }
  }
  // pos rows 128..135 (same multiplier both routings)
  #pragma unroll 2
  for (int i = 0; i < 8; ++i) {
    float p = SB[PP + i * 65 + sq];
    const v4f* w = (const v4f*)(SB + (128 + i) * 64 + jq * 16);
    v4f pv = {p, p, p, p};
    #pragma unroll
    for (int e = 0; e < 4; e++) {
      v4f wv = w[e];
      acc1[e] = __builtin_elementwise_fma(pv, wv, acc1[e]);
      acc2[e] = __builtin_elementwise_fma(pv, wv, acc2[e]);
    }
  }
  // gelu in place
  #pragma unroll
  for (int e = 0; e < 4; e++) {
    #pragma unroll
    for (int c = 0; c < 4; c++) {
      acc1[e][c] = gelu_f(acc1[e][c]);
      acc2[e][c] = gelu_f(acc2[e][c]);
    }
  }
  __syncthreads();   // all X/P reads done before h overwrites the X region
  #pragma unroll
  for (int e = 0; e < 4; e++) {
    #pragma unroll
    for (int c = 0; c < 4; c++) {
      int j = jq * 16 + e * 4 + c;
      SB[XA + j * 65 + sq] = acc1[e][c];
      SB[XB + j * 65 + sq] = acc2[e][c];
    }
  }
  __syncthreads();
  // layer 2: ordered sum j = 0..63 (exact round-0 sequence)
  v4f l1 = *(const v4f*)(SB + 141 * 64);
  v4f l2 = l1;
  #pragma unroll 4
  for (int j = 0; j < 64; ++j) {
    float h1 = SB[XA + j * 65 + sq];
    float h2 = SB[XB + j * 65 + sq];
    v4f w2 = *(const v4f*)(SB + 137 * 64 + j * 4);
    v4f h1v = {h1, h1, h1, h1}, h2v = {h2, h2, h2, h2};
    l1 = __builtin_elementwise_fma(h1v, w2, l1);
    l2 = __builtin_elementwise_fma(h2v, w2, l2);
  }
  int idx1 = 0; float b1v = l1[0];
  if (l1[1] > b1v) { b1v = l1[1]; idx1 = 1; }
  if (l1[2] > b1v) { b1v = l1[2]; idx1 = 2; }
  if (l1[3] > b1v) { b1v = l1[3]; idx1 = 3; }
  int idx2 = 0; float b2v = l2[0];
  if (l2[1] > b2v) { b2v = l2[1]; idx2 = 1; }
  if (l2[2] > b2v) { b2v = l2[2]; idx2 = 2; }
  if (l2[3] > b2v) { b2v = l2[3]; idx2 = 3; }
  if (jq == 0) {
    r1[s0 + sq] = (unsigned char)idx1;
    r2[s0 + sq] = (unsigned char)idx2;
    atomicAdd(&hcnt[idx1], 1u);
    atomicAdd(&hcnt[idx2], 1u);
  }
  __syncthreads();
  if (tid < 4) atomicAdd(&gcounts[tid], hcnt[tid]);
}

// ---------------- K2b: padded bucket offsets + sentinel fill ----------------
// table[t] = padded start of bucket t (multiples of 128), table[4] = padded total.
__global__ __launch_bounds__(256) void offsets_k(
    const unsigned int* __restrict__ counts, unsigned int* __restrict__ table,
    unsigned int* __restrict__ cursors, unsigned int* __restrict__ list) {
  __shared__ unsigned int ps[5], cnt[4];
  int tid = threadIdx.x;
  if (tid == 0) {
    unsigned int acc = 0;
    for (int t = 0; t < 4; t++) {
      ps[t] = acc;
      unsigned int c = counts[t];
      cnt[t] = c;
      acc += ((c + 127u) >> 7) << 7;
    }
    ps[4] = acc;
    #pragma unroll
    for (int t = 0; t < 5; t++) table[t] = ps[t];
    #pragma unroll
    for (int t = 0; t < 4; t++) cursors[t] = ps[t];
  }
  __syncthreads();
  #pragma unroll
  for (int r = 0; r < 2; r++) {
    int idx = r * 256 + tid;
    int t = idx >> 7, i = idx & 127;
    unsigned int pos = ps[t] + cnt[t] + (unsigned int)i;
    if (pos < ps[t + 1]) list[pos] = 0xFFFFFFFFu;   // sentinel pad
  }
}

// ---------------- K2c: scatter pairs into bucketed list ----------------
// entry = (s << 1) | rb ; rb=0 -> out1 (expert r1[s]), rb=1 -> out2 (expert r2[s])
__global__ __launch_bounds__(256) void place_k(
    const unsigned char* __restrict__ r1, const unsigned char* __restrict__ r2,
    unsigned int* __restrict__ cursors, unsigned int* __restrict__ list) {
  __shared__ unsigned int lc[4], lb[4];
  int tid = threadIdx.x;
  if (tid < 4) lc[tid] = 0u;
  __syncthreads();
  int s = blockIdx.x * 256 + tid;
  int e1 = (int)r1[s], e2 = (int)r2[s];
  unsigned int k1 = atomicAdd(&lc[e1], 1u);
  unsigned int k2 = atomicAdd(&lc[e2], 1u);
  __syncthreads();
  if (tid < 4) lb[tid] = atomicAdd(&cursors[tid], lc[tid]);
  __syncthreads();
  list[lb[e1] + k1] = ((unsigned int)s << 1);
  list[lb[e2] + k2] = ((unsigned int)s << 1) | 1u;
}

// ---------------- K3: routed experts — ONE expert per block, 128 pairs ----------
// Same MFMA/gelu/bpermute arithmetic as the round-0 expert2_k (bit-identical for
// the selected expert); only the discarded 3 experts' work is eliminated.
__global__ __launch_bounds__(256) void expert3_k(
    const float* __restrict__ a, const float* __restrict__ b,
    const short* __restrict__ W1s, const short* __restrict__ W2s,
    const float* __restrict__ b1, const float* __restrict__ b2,
    const unsigned int* __restrict__ table, const unsigned int* __restrict__ list,
    float* __restrict__ out) {
  __shared__ short LB[24576];       // 48KB; overlaid: pair-frag staging then weights
  __shared__ unsigned int eLS[128];
  int tid = threadIdx.x;
  int wave = tid >> 6, lane = tid & 63;
  int q = lane >> 4, sm = lane & 15;

  unsigned int p0 = blockIdx.x * 128u;
  unsigned int t1 = table[1], t2 = table[2], t3 = table[3], t4 = table[4];
  if (p0 >= t4) return;             // uniform early-exit (no barriers yet)
  int t = (p0 >= t1) + (p0 >= t2) + (p0 >= t3);   // bucket = expert id

  if (tid < 128) eLS[tid] = list[p0 + tid];
  __syncthreads();

  // stage pair^T B-fragments for both 64-pair groups (lane-linear 16B slots)
  #pragma unroll
  for (int r = 0; r < 8; r++) {
    int slot = r * 256 + tid;                 // 2048 slots
    int g = slot >> 10, sg = slot & 1023;
    int f = sg >> 6, l = sg & 63;
    int sgrp = f >> 2, kb = f & 3;
    int ls2 = g * 64 + sgrp * 16 + (l & 15);
    unsigned int e = eLS[ls2];
    int s = (e == 0xFFFFFFFFu) ? 0 : (int)(e >> 1);
    int k = kb * 32 + (l >> 4) * 8;
    const float* src = (k < 64) ? (a + (size_t)s * 64 + k) : (b + (size_t)s * 64 + (k - 64));
    acc_t v0 = *(const acc_t*)(src);
    acc_t v1 = *(const acc_t*)(src + 4);
    i32x4_t pk;
    pk[0] = (int)pk2bf(v0[0], v0[1]);
    pk[1] = (int)pk2bf(v0[2], v0[3]);
    pk[2] = (int)pk2bf(v1[0], v1[1]);
    pk[3] = (int)pk2bf(v1[2], v1[3]);
    *(i32x4_t*)(&LB[slot * 8]) = pk;
  }
  __syncthreads();
  bfrag_t bfrag[2][4];
  #pragma unroll
  for (int g = 0; g < 2; g++)
    #pragma unroll
    for (int kb = 0; kb < 4; kb++)
      bfrag[g][kb] = *(const bfrag_t*)(&LB[((g * 16 + wave * 4 + kb) * 64 + lane) * 8]);

  unsigned int eA = eLS[wave * 16 + sm];
  unsigned int eB = eLS[64 + wave * 16 + sm];
  __syncthreads();   // all frag reads done before weights overwrite LB

  acc_t zero = {0.f, 0.f, 0.f, 0.f};
  int vb[4];
  #pragma unroll
  for (int kb = 0; kb < 4; kb++) vb[kb] = sm * 256 + (((kb * 4 + q) ^ sm) * 16);
  int addr0 = (((q & 1) * 2) * 16 + sm) * 4;
  int addr1 = addr0 + 64;
  bool hi = (q >> 1) != 0;

  // stage expert t's weights: W1s 32KB (2048 chunks) + W2s 16KB (1024 chunks)
  #pragma unroll
  for (int it = 0; it < 12; it++) {
    int cb = it * 256 + wave * 64;          // wave-uniform base
    int chunk = cb + lane;
    const short* gsrc = (chunk < 2048) ? (W1s + t * 16384 + chunk * 8)
                                       : (W2s + t * 8192 + (chunk - 2048) * 8);
    gload_lds16(gsrc, (char*)LB + cb * 16);
  }
  __syncthreads();

  #pragma unroll
  for (int g = 0; g < 2; g++) {
    // layer 1: h^T
    unsigned int hp[8][2];
    #pragma unroll
    for (int mt = 0; mt < 8; mt++) {
      acc_t c = zero;
      #pragma unroll
      for (int kb = 0; kb < 4; kb++) {
        bfrag_t A = *(const bfrag_t*)((const char*)LB + mt * 4096 + vb[kb]);
        c = __builtin_amdgcn_mfma_f32_16x16x32_bf16(A, bfrag[g][kb], c, 0, 0, 0);
      }
      acc_t bv = *(const acc_t*)(b1 + t * 128 + mt * 16 + q * 4);
      float g0 = gelu_f(c[0] + bv[0]);
      float g1 = gelu_f(c[1] + bv[1]);
      float g2 = gelu_f(c[2] + bv[2]);
      float g3 = gelu_f(c[3] + bv[3]);
      hp[mt][0] = pk2bf(g0, g1);
      hp[mt][1] = pk2bf(g2, g3);
    }
    // redistribute h^T C-frags -> layer-2 B-frags (wave-local bpermute)
    bfrag_t b2f[4];
    #pragma unroll
    for (int kb2 = 0; kb2 < 4; kb2++) {
      int p00 = __builtin_amdgcn_ds_bpermute(addr0, (int)hp[2 * kb2][0]);
      int p01 = __builtin_amdgcn_ds_bpermute(addr0, (int)hp[2 * kb2][1]);
      int p10 = __builtin_amdgcn_ds_bpermute(addr1, (int)hp[2 * kb2][0]);
      int p11 = __builtin_amdgcn_ds_bpermute(addr1, (int)hp[2 * kb2][1]);
      int q00 = __builtin_amdgcn_ds_bpermute(addr0, (int)hp[2 * kb2 + 1][0]);
      int q01 = __builtin_amdgcn_ds_bpermute(addr0, (int)hp[2 * kb2 + 1][1]);
      int q10 = __builtin_amdgcn_ds_bpermute(addr1, (int)hp[2 * kb2 + 1][0]);
      int q11 = __builtin_amdgcn_ds_bpermute(addr1, (int)hp[2 * kb2 + 1][1]);
      i32x4_t w;
      w[0] = hi ? q00 : p00;
      w[1] = hi ? q01 : p01;
      w[2] = hi ? q10 : p10;
      w[3] = hi ? q11 : p11;
      b2f[kb2] = __builtin_bit_cast(bfrag_t, w);
    }
    // layer 2 + guarded routed store
    unsigned int e = g ? eB : eA;
    bool live = (e != 0xFFFFFFFFu);
    size_t so = ((size_t)(e & 1u)) * B_N + (size_t)(e >> 1);
    float* p = out + so * 64 + q * 4;
    #pragma unroll
    for (int mt2 = 0; mt2 < 4; mt2++) {
      acc_t c = zero;
      #pragma unroll
      for (int kb2 = 0; kb2 < 4; kb2++) {
        bfrag_t A = *(const bfrag_t*)((const char*)LB + 32768 + mt2 * 4096 + vb[kb2]);
        c = __builtin_amdgcn_mfma_f32_16x16x32_bf16(A, b2f[kb2], c, 0, 0, 0);
      }
      acc_t bv = *(const acc_t*)(b2 + t * 64 + mt2 * 16 + q * 4);
      c[0] += bv[0]; c[1] += bv[1]; c[2] += bv[2]; c[3] += bv[3];
      if (live) *(acc_t*)(p + mt2 * 16) = c;
    }
  }
}

extern "C" void kernel_launch(void* const* d_in, const int* in_sizes, int n_in,
                              void* d_out, int out_size, void* d_ws, size_t ws_size,
                              hipStream_t stream) {
  const float* a   = (const float*)d_in[0];
  const float* bv  = (const float*)d_in[1];
  const float* pos = (const float*)d_in[2];
  const float* Wr1 = (const float*)d_in[3];
  const float* br1 = (const float*)d_in[4];
  const float* Wr2 = (const float*)d_in[5];
  const float* br2 = (const float*)d_in[6];
  const float* W1  = (const float*)d_in[7];
  const float* b1  = (const float*)d_in[8];
  const float* W2  = (const float*)d_in[9];
  const float* b2  = (const float*)d_in[10];
  float* out = (float*)d_out;

  // ws layout (BYTES):
  // r1 [0,131072) r2 [131072,262144) RW [262144,298496)
  // W1s [298496,429568) W2s [429568,495104)
  // counts [495104,495120) cursors [495120,495136) table [495136,495156)
  // list [495168, 495168+1050608) -- 262144 pairs + <=508 pad sentinels
  unsigned char* r1 = (unsigned char*)d_ws;
  unsigned char* r2 = r1 + B_N;
  float* RW  = (float*)((char*)d_ws + 262144);
  short* W1s = (short*)((char*)d_ws + 298496);
  short* W2s = (short*)((char*)d_ws + 429568);
  unsigned int* counts  = (unsigned int*)((char*)d_ws + 495104);
  unsigned int* cursors = (unsigned int*)((char*)d_ws + 495120);
  unsigned int* table   = (unsigned int*)((char*)d_ws + 495136);
  unsigned int* list    = (unsigned int*)((char*)d_ws + 495168);

  prepack2_k<<<64, 256, 0, stream>>>(Wr1, br1, Wr2, br2, W1, W2, RW, W1s, W2s, counts);
  router7_k<<<B_N / 64, 256, 0, stream>>>(a, bv, pos, RW, r1, r2, counts);
  offsets_k<<<1, 256, 0, stream>>>(counts, table, cursors, list);
  place_k<<<B_N / 256, 256, 0, stream>>>(r1, r2, cursors, list);
  expert3_k<<<2052, 256, 0, stream>>>(a, bv, W1s, W2s, b1, b2, table, list, out);
}